// Round 2
// baseline (310.467 us; speedup 1.0000x reference)
//
#include <hip/hip_runtime.h>

#define Bsz  16
#define Ch   256
#define Tlen 2048
#define Kcb  1024

#define TQ     64   // queries (t) per block
#define KCHUNK 256  // codebook rows per outer chunk (64 per wave)
#define CC     32   // channels per LDS sub-stage

// Prep: codebookT[c][k] for coalesced staging, cnorm[k] = 0.5*||c_k||^2
__global__ __launch_bounds__(256) void vq_prep(const float* __restrict__ cb,
                                               float* __restrict__ cbT,
                                               float* __restrict__ cnorm) {
  int k = blockIdx.x;
  int c = threadIdx.x;
  float v = cb[k * Ch + c];
  cbT[(size_t)c * Kcb + k] = v;
  float s = v * v;
  #pragma unroll
  for (int off = 32; off > 0; off >>= 1) s += __shfl_down(s, off, 64);
  __shared__ float wsum[4];
  if ((threadIdx.x & 63) == 0) wsum[threadIdx.x >> 6] = s;
  __syncthreads();
  if (threadIdx.x == 0) cnorm[k] = 0.5f * (wsum[0] + wsum[1] + wsum[2] + wsum[3]);
}

__global__ __launch_bounds__(256, 2) void vq_main(const float* __restrict__ z,
                                                  const float* __restrict__ cbT,
                                                  const float* __restrict__ cnorm,
                                                  float* __restrict__ out) {
  __shared__ float q_lds[CC][TQ];        // 8 KB
  __shared__ float cb_lds[CC][KCHUNK];   // 32 KB
  __shared__ float red_val[4][TQ];
  __shared__ int   red_idx[4][TQ];
  __shared__ int   best_sh[TQ];

  const int tid  = threadIdx.x;
  const int w    = tid >> 6;     // wave 0..3
  const int lane = tid & 63;
  const int ki   = lane & 7;     // k-group within wave
  const int qi   = lane >> 3;    // q-group within wave

  const int b  = blockIdx.x >> 5;         // T/TQ = 32 tiles per batch
  const int t0 = (blockIdx.x & 31) * TQ;

  float bestv[8];
  int   besti[8];
  #pragma unroll
  for (int j = 0; j < 8; ++j) { bestv[j] = -3.4e38f; besti[j] = 0; }

  for (int kc = 0; kc < Kcb; kc += KCHUNK) {
    float acc[8][8];
    #pragma unroll
    for (int a = 0; a < 8; ++a)
      #pragma unroll
      for (int bb = 0; bb < 8; ++bb) acc[a][bb] = 0.f;

    for (int c0 = 0; c0 < Ch; c0 += CC) {
      __syncthreads();  // protect LDS reuse from previous sub-stage
      // stage q tile: CC x TQ  (t contiguous -> coalesced float4)
      {
        int tj = (tid & 15) * 4;
        #pragma unroll
        for (int i = 0; i < 2; ++i) {
          int ci = i * 16 + (tid >> 4);
          const float4 v = *reinterpret_cast<const float4*>(
              &z[((size_t)(b * Ch + c0 + ci)) * Tlen + t0 + tj]);
          *reinterpret_cast<float4*>(&q_lds[ci][tj]) = v;
        }
      }
      // stage cb tile: CC x KCHUNK from cbT (k contiguous -> coalesced float4)
      {
        int kk = (tid & 63) * 4;
        #pragma unroll
        for (int i = 0; i < 8; ++i) {
          int ci = i * 4 + w;
          const float4 v = *reinterpret_cast<const float4*>(
              &cbT[(size_t)(c0 + ci) * Kcb + kc + kk]);
          *reinterpret_cast<float4*>(&cb_lds[ci][kk]) = v;
        }
      }
      __syncthreads();

      #pragma unroll 4
      for (int c = 0; c < CC; ++c) {
        float4 qa = *reinterpret_cast<const float4*>(&q_lds[c][qi * 8]);
        float4 qb = *reinterpret_cast<const float4*>(&q_lds[c][qi * 8 + 4]);
        float4 ka = *reinterpret_cast<const float4*>(&cb_lds[c][w * 64 + ki * 8]);
        float4 kb = *reinterpret_cast<const float4*>(&cb_lds[c][w * 64 + ki * 8 + 4]);
        float qv[8] = {qa.x, qa.y, qa.z, qa.w, qb.x, qb.y, qb.z, qb.w};
        float kv[8] = {ka.x, ka.y, ka.z, ka.w, kb.x, kb.y, kb.z, kb.w};
        #pragma unroll
        for (int a = 0; a < 8; ++a)
          #pragma unroll
          for (int bb = 0; bb < 8; ++bb)
            acc[a][bb] = fmaf(qv[a], kv[bb], acc[a][bb]);
      }
    }

    // argmax update for this k-chunk: maximize s - 0.5*||c||^2
    const int kbase = kc + w * 64 + ki * 8;
    float ck[8];
    #pragma unroll
    for (int j = 0; j < 8; ++j) ck[j] = cnorm[kbase + j];
    #pragma unroll
    for (int a = 0; a < 8; ++a) {
      #pragma unroll
      for (int j = 0; j < 8; ++j) {
        float v = acc[a][j] - ck[j];
        if (v > bestv[a]) { bestv[a] = v; besti[a] = kbase + j; }  // strict >, k ascending -> first-index ties
      }
    }
  }

  // reduce across the 8 k-lanes (lane bits 0..2)
  #pragma unroll
  for (int step = 1; step < 8; step <<= 1) {
    #pragma unroll
    for (int a = 0; a < 8; ++a) {
      float ov = __shfl_xor(bestv[a], step, 64);
      int   oi = __shfl_xor(besti[a], step, 64);
      if (ov > bestv[a] || (ov == bestv[a] && oi < besti[a])) {
        bestv[a] = ov; besti[a] = oi;
      }
    }
  }
  if (ki == 0) {
    #pragma unroll
    for (int a = 0; a < 8; ++a) {
      red_val[w][qi * 8 + a] = bestv[a];
      red_idx[w][qi * 8 + a] = besti[a];
    }
  }
  __syncthreads();
  if (tid < TQ) {
    float v = red_val[0][tid]; int idx = red_idx[0][tid];
    #pragma unroll
    for (int ww = 1; ww < 4; ++ww) {
      float ov = red_val[ww][tid]; int oi = red_idx[ww][tid];
      if (ov > v || (ov == v && oi < idx)) { v = ov; idx = oi; }
    }
    best_sh[tid] = idx;
    // indices output (as float values; d_out is read as one float32 buffer)
    out[(size_t)Bsz * Ch * Tlen + (size_t)b * Tlen + t0 + tid] = (float)idx;
  }
  __syncthreads();

  // epilogue: z_q[b][c][t0+t] = codebook[idx[t]][c]; t-contiguous coalesced stores
  {
    const int t   = tid & 63;
    const int idx = best_sh[t];
    #pragma unroll 4
    for (int it = 0; it < 64; ++it) {
      int c = it * 4 + w;
      out[((size_t)(b * Ch + c)) * Tlen + t0 + t] = cbT[(size_t)c * Kcb + idx];
    }
  }
}

extern "C" void kernel_launch(void* const* d_in, const int* in_sizes, int n_in,
                              void* d_out, int out_size, void* d_ws, size_t ws_size,
                              hipStream_t stream) {
  const float* z  = (const float*)d_in[0];
  const float* cb = (const float*)d_in[1];
  float* out   = (float*)d_out;
  float* cbT   = (float*)d_ws;               // 256*1024 floats = 1 MB
  float* cnorm = cbT + (size_t)Ch * Kcb;     // 1024 floats

  vq_prep<<<Kcb, Ch, 0, stream>>>(cb, cbT, cnorm);
  vq_main<<<(Bsz * Tlen) / TQ, 256, 0, stream>>>(z, cbT, cnorm, out);
}